// Round 9
// baseline (347.258 us; speedup 1.0000x reference)
//
#include <hip/hip_runtime.h>
#include <hip/hip_bf16.h>

#define B_ 8
#define T_ 768
#define H_ 128
#define F_ 10

// ---------------------------------------------------------------------------
// r9_T: VT[b][h][j] = V[b][j][h]   (tiled f32 transpose, coalesced both sides)
// grid = 8 * 24 * 4 = 768 blocks, 256 threads (32x8 tile workers)
// ---------------------------------------------------------------------------
__global__ __launch_bounds__(256) void r9_T(const float* __restrict__ V,
                                            float* __restrict__ VT) {
  __shared__ float tile[32][33];
  const int blk = blockIdx.x;
  const int ht = blk % (H_ / 32);
  const int it = (blk / (H_ / 32)) % (T_ / 32);
  const int b  = blk / ((H_ / 32) * (T_ / 32));
  const int tx = threadIdx.x & 31;
  const int ty = threadIdx.x >> 5;  // 0..7

  const float* Vb = V + (size_t)b * T_ * H_;
#pragma unroll
  for (int r = ty; r < 32; r += 8)
    tile[r][tx] = Vb[(size_t)(it * 32 + r) * H_ + ht * 32 + tx];
  __syncthreads();
  float* VTb = VT + (size_t)b * H_ * T_;
#pragma unroll
  for (int r = ty; r < 32; r += 8)
    VTb[(size_t)(ht * 32 + r) * T_ + it * 32 + tx] = tile[tx][r];
}

// ---------------------------------------------------------------------------
// r9_A: UT[b][f][k][i] = sum_h V[b][i][h] * W[f][h][k]   (all f32)
// One (b, f, 64-i tile) per block; k split into two 64-wide passes.
// LDS = 32 KB (sW half) + 32 KB (sVT) = 64 KB. grid = 8*10*12 = 960.
// ---------------------------------------------------------------------------
__global__ __launch_bounds__(256) void r9_A(const float* __restrict__ VT,
                                            const float* __restrict__ W,
                                            float* __restrict__ UT) {
  __shared__ __align__(16) float sW[128][64];   // [h][k-half]
  __shared__ __align__(16) float sVT[128][64];  // [h][i]
  const int blk = blockIdx.x;
  const int it = blk % (T_ / 64);
  const int f  = (blk / (T_ / 64)) % F_;
  const int b  = blk / ((T_ / 64) * F_);
  const int t  = threadIdx.x;
  const int tr = t >> 4;  // k-group within half
  const int tc = t & 15;  // i-group

  {  // stage sVT once: rows of VT (no transpose needed)
    const float* VTb = VT + (size_t)b * H_ * T_ + it * 64;
    for (int p = t; p < 128 * 16; p += 256) {
      const int h = p >> 4, c = p & 15;
      *reinterpret_cast<float4*>(&sVT[h][c * 4]) =
          *reinterpret_cast<const float4*>(&VTb[(size_t)h * T_ + c * 4]);
    }
  }

  const float* Wf = W + (size_t)f * H_ * H_;
  for (int kp = 0; kp < 2; ++kp) {
    if (kp) __syncthreads();  // prior pass's sW reads complete
    for (int p = t; p < 128 * 16; p += 256) {
      const int h = p >> 4, c = p & 15;
      *reinterpret_cast<float4*>(&sW[h][c * 4]) =
          *reinterpret_cast<const float4*>(&Wf[(size_t)h * H_ + kp * 64 + c * 4]);
    }
    __syncthreads();  // sW ready (and sVT on kp=0)

    float acc[4][4] = {};
#pragma unroll 2
    for (int h = 0; h < H_; ++h) {
      const float4 a = *reinterpret_cast<const float4*>(&sW[h][tr * 4]);
      const float4 v = *reinterpret_cast<const float4*>(&sVT[h][tc * 4]);
      acc[0][0] += a.x * v.x; acc[0][1] += a.x * v.y; acc[0][2] += a.x * v.z; acc[0][3] += a.x * v.w;
      acc[1][0] += a.y * v.x; acc[1][1] += a.y * v.y; acc[1][2] += a.y * v.z; acc[1][3] += a.y * v.w;
      acc[2][0] += a.z * v.x; acc[2][1] += a.z * v.y; acc[2][2] += a.z * v.z; acc[2][3] += a.z * v.w;
      acc[3][0] += a.w * v.x; acc[3][1] += a.w * v.y; acc[3][2] += a.w * v.z; acc[3][3] += a.w * v.w;
    }
#pragma unroll
    for (int q = 0; q < 4; ++q) {
      const int k = kp * 64 + tr * 4 + q;
      float4 o = make_float4(acc[q][0], acc[q][1], acc[q][2], acc[q][3]);
      *reinterpret_cast<float4*>(
          &UT[((size_t)(b * F_ + f) * H_ + k) * T_ + it * 64 + tc * 4]) = o;
    }
  }
}

// ---------------------------------------------------------------------------
// r9_B: S[b][i][j] = max_f sum_k UT[b][f][k][i] * VT[b][k][j]   (all f32)
// One (b, 64-i, 64-j) per block; thread 4x4. LDS = 64 KB. grid = 1152.
// ---------------------------------------------------------------------------
__global__ __launch_bounds__(256) void r9_B(const float* __restrict__ VT,
                                            const float* __restrict__ UT,
                                            float* __restrict__ S) {
  __shared__ __align__(16) float sA[128][64];  // U^T tile [k][i]
  __shared__ __align__(16) float sB[128][64];  // V^T tile [k][j]
  const int blk = blockIdx.x;
  const int jt = blk % (T_ / 64);
  const int it = (blk / (T_ / 64)) % (T_ / 64);
  const int b  = blk / ((T_ / 64) * (T_ / 64));
  const int t  = threadIdx.x;
  const int tr = t >> 4;  // i rows
  const int tc = t & 15;  // j cols

  {  // stage sB once: rows of VT (no transpose)
    const float* VTb = VT + (size_t)b * H_ * T_ + jt * 64;
    for (int p = t; p < 128 * 16; p += 256) {
      const int k = p >> 4, c = p & 15;
      *reinterpret_cast<float4*>(&sB[k][c * 4]) =
          *reinterpret_cast<const float4*>(&VTb[(size_t)k * T_ + c * 4]);
    }
  }

  float smax[4][4];
#pragma unroll
  for (int q = 0; q < 4; ++q)
#pragma unroll
    for (int p = 0; p < 4; ++p) smax[q][p] = -3.4e38f;

  for (int f = 0; f < F_; ++f) {
    __syncthreads();  // sB ready (f=0) / prior sA reads done (f>0)
    const float* Ua = UT + (size_t)(b * F_ + f) * H_ * T_ + it * 64;
    for (int p4 = t; p4 < 128 * 16; p4 += 256) {
      const int k = p4 >> 4, i0 = (p4 & 15) * 4;
      *reinterpret_cast<float4*>(&sA[k][i0]) =
          *reinterpret_cast<const float4*>(&Ua[(size_t)k * T_ + i0]);
    }
    __syncthreads();

    float acc[4][4] = {};
#pragma unroll 2
    for (int k = 0; k < H_; ++k) {
      const float4 a = *reinterpret_cast<const float4*>(&sA[k][tr * 4]);
      const float4 bv = *reinterpret_cast<const float4*>(&sB[k][tc * 4]);
      acc[0][0] += a.x * bv.x; acc[0][1] += a.x * bv.y; acc[0][2] += a.x * bv.z; acc[0][3] += a.x * bv.w;
      acc[1][0] += a.y * bv.x; acc[1][1] += a.y * bv.y; acc[1][2] += a.y * bv.z; acc[1][3] += a.y * bv.w;
      acc[2][0] += a.z * bv.x; acc[2][1] += a.z * bv.y; acc[2][2] += a.z * bv.z; acc[2][3] += a.z * bv.w;
      acc[3][0] += a.w * bv.x; acc[3][1] += a.w * bv.y; acc[3][2] += a.w * bv.z; acc[3][3] += a.w * bv.w;
    }
#pragma unroll
    for (int q = 0; q < 4; ++q)
#pragma unroll
      for (int p = 0; p < 4; ++p) smax[q][p] = fmaxf(smax[q][p], acc[q][p]);
  }

#pragma unroll
  for (int q = 0; q < 4; ++q) {
    float4 o = make_float4(smax[q][0], smax[q][1], smax[q][2], smax[q][3]);
    *reinterpret_cast<float4*>(
        &S[(size_t)(b * T_ + it * 64 + tr * 4 + q) * T_ + jt * 64 + tc * 4]) = o;
  }
}

// ---------------------------------------------------------------------------
// r9_C: row softmax of S, then O = P @ V.  All f32.
// 256 thr = 16 rows x 16 lanes, one (b, 16-row i-tile). grid = 8*48 = 384.
// ---------------------------------------------------------------------------
__global__ __launch_bounds__(256) void r9_C(const float* __restrict__ V,
                                            const float* __restrict__ S,
                                            float* __restrict__ O) {
  __shared__ __align__(16) float sP[16][772];
  const int blk = blockIdx.x;
  const int it = blk % (T_ / 16);
  const int b  = blk / (T_ / 16);
  const int t  = threadIdx.x;
  const int r  = t >> 4;
  const int c  = t & 15;

  const float* Srow = S + (size_t)(b * T_ + it * 16) * T_;

  float4 buf[12];
  float m = -3.4e38f;
#pragma unroll
  for (int q = 0; q < 12; ++q) {
    const int j4 = c + q * 16;
    const float4 x = *reinterpret_cast<const float4*>(&Srow[r * T_ + j4 * 4]);
    buf[q] = x;
    m = fmaxf(m, fmaxf(fmaxf(x.x, x.y), fmaxf(x.z, x.w)));
  }
  m = fmaxf(m, __shfl_xor(m, 1));
  m = fmaxf(m, __shfl_xor(m, 2));
  m = fmaxf(m, __shfl_xor(m, 4));
  m = fmaxf(m, __shfl_xor(m, 8));

  float l = 0.f;
#pragma unroll
  for (int q = 0; q < 12; ++q) {
    const int j4 = c + q * 16;
    float4 e;
    e.x = expf(buf[q].x - m);
    e.y = expf(buf[q].y - m);
    e.z = expf(buf[q].z - m);
    e.w = expf(buf[q].w - m);
    l += (e.x + e.y) + (e.z + e.w);
    *reinterpret_cast<float4*>(&sP[r][j4 * 4]) = e;
  }
  l += __shfl_xor(l, 1);
  l += __shfl_xor(l, 2);
  l += __shfl_xor(l, 4);
  l += __shfl_xor(l, 8);
  __syncthreads();

  const float inv = 1.0f / l;
  float acc[8] = {};
  const float* Vb = V + (size_t)b * T_ * H_ + c * 8;
#pragma unroll 8
  for (int j = 0; j < T_; ++j) {
    const float p = sP[r][j];
    const float4 v0 = *reinterpret_cast<const float4*>(&Vb[(size_t)j * H_]);
    const float4 v1 = *reinterpret_cast<const float4*>(&Vb[(size_t)j * H_ + 4]);
    acc[0] += p * v0.x; acc[1] += p * v0.y; acc[2] += p * v0.z; acc[3] += p * v0.w;
    acc[4] += p * v1.x; acc[5] += p * v1.y; acc[6] += p * v1.z; acc[7] += p * v1.w;
  }
  float4 o0 = make_float4(acc[0] * inv, acc[1] * inv, acc[2] * inv, acc[3] * inv);
  float4 o1 = make_float4(acc[4] * inv, acc[5] * inv, acc[6] * inv, acc[7] * inv);
  float* Orow = O + (size_t)(b * T_ + it * 16 + r) * H_ + c * 8;
  *reinterpret_cast<float4*>(&Orow[0]) = o0;
  *reinterpret_cast<float4*>(&Orow[4]) = o1;
}

// ---------------------------------------------------------------------------
extern "C" void kernel_launch(void* const* d_in, const int* in_sizes, int n_in,
                              void* d_out, int out_size, void* d_ws, size_t ws_size,
                              hipStream_t stream) {
  const float* V = (const float*)d_in[0];  // f32 [B,T,H] = 786432 elems
  const float* W = (const float*)d_in[1];  // f32 [F,H,H] = 163840 elems
  if (n_in >= 2 && in_sizes[0] == F_ * H_ * H_) {  // defensive swap
    V = (const float*)d_in[1];
    W = (const float*)d_in[0];
  }
  float* O = (float*)d_out;  // f32 [B,T,H]

  const size_t vt_elems = (size_t)B_ * H_ * T_;      //   786,432
  const size_t u_elems  = (size_t)B_ * F_ * H_ * T_; // 7,864,320
  const size_t s_elems  = (size_t)B_ * T_ * T_;      // 4,718,592
  const size_t need = (vt_elems + u_elems + s_elems) * sizeof(float);  // ~53.5 MB
  if (ws_size < need) return;

  float* VT = (float*)d_ws;
  float* UT = VT + vt_elems;
  float* S  = UT + u_elems;

  r9_T<<<B_ * (T_ / 32) * (H_ / 32), 256, 0, stream>>>(V, VT);
  r9_A<<<B_ * F_ * (T_ / 64), 256, 0, stream>>>(VT, W, UT);
  r9_B<<<B_ * (T_ / 64) * (T_ / 64), 256, 0, stream>>>(VT, UT, S);
  r9_C<<<B_ * (T_ / 16), 256, 0, stream>>>(V, S, O);
}

// Round 10
// 188.256 us; speedup vs baseline: 1.8446x; 1.8446x over previous
//
#include <hip/hip_runtime.h>
#include <hip/hip_bf16.h>

#define B_ 8
#define T_ 768
#define H_ 128
#define F_ 10

using short8v = __attribute__((ext_vector_type(8))) short;
using f32x4   = __attribute__((ext_vector_type(4))) float;

__device__ __forceinline__ float bf2f(unsigned short s) {
  union { unsigned int u; float f; } w;
  w.u = ((unsigned int)s) << 16;
  return w.f;
}
__device__ __forceinline__ unsigned short f2bf(float x) {
  __hip_bfloat16 h = __float2bfloat16(x);  // RN
  return *reinterpret_cast<unsigned short*>(&h);
}
union Pk8 { uint4 u4; unsigned short s[8]; };

// ---------------------------------------------------------------------------
// r9_T: VT[b][h][j] = V[b][j][h]  (unchanged, verified)
// ---------------------------------------------------------------------------
__global__ __launch_bounds__(256) void r9_T(const float* __restrict__ V,
                                            float* __restrict__ VT) {
  __shared__ float tile[32][33];
  const int blk = blockIdx.x;
  const int ht = blk % (H_ / 32);
  const int it = (blk / (H_ / 32)) % (T_ / 32);
  const int b  = blk / ((H_ / 32) * (T_ / 32));
  const int tx = threadIdx.x & 31;
  const int ty = threadIdx.x >> 5;

  const float* Vb = V + (size_t)b * T_ * H_;
#pragma unroll
  for (int r = ty; r < 32; r += 8)
    tile[r][tx] = Vb[(size_t)(it * 32 + r) * H_ + ht * 32 + tx];
  __syncthreads();
  float* VTb = VT + (size_t)b * H_ * T_;
#pragma unroll
  for (int r = ty; r < 32; r += 8)
    VTb[(size_t)(ht * 32 + r) * T_ + it * 32 + tx] = tile[tx][r];
}

// ---------------------------------------------------------------------------
// r10_A: U[b][f][k][i] computed in f32 (verified r9_A compute), written as
// MFMA A-fragment-major bf16 hi/lo:  frag = ((b*F+f)*48 + itile)*4 + ks,
// within frag: lane*8+e where lane=(i&15)+16*((k>>3)&3), e=k&7.
// LDS 64 KB. grid = 8*10*12 = 960.
// ---------------------------------------------------------------------------
__global__ __launch_bounds__(256) void r10_A(const float* __restrict__ VT,
                                             const float* __restrict__ W,
                                             unsigned short* __restrict__ UFh,
                                             unsigned short* __restrict__ UFl) {
  __shared__ __align__(16) float sW[128][64];
  __shared__ __align__(16) float sVT[128][64];
  const int blk = blockIdx.x;
  const int it = blk % (T_ / 64);
  const int f  = (blk / (T_ / 64)) % F_;
  const int b  = blk / ((T_ / 64) * F_);
  const int t  = threadIdx.x;
  const int tr = t >> 4;  // k-group within 64-half
  const int tc = t & 15;  // i-group

  {
    const float* VTb = VT + (size_t)b * H_ * T_ + it * 64;
    for (int p = t; p < 128 * 16; p += 256) {
      const int h = p >> 4, c = p & 15;
      *reinterpret_cast<float4*>(&sVT[h][c * 4]) =
          *reinterpret_cast<const float4*>(&VTb[(size_t)h * T_ + c * 4]);
    }
  }

  float acc2[2][4][4];
#pragma unroll
  for (int kp = 0; kp < 2; ++kp)
#pragma unroll
    for (int q = 0; q < 4; ++q)
#pragma unroll
      for (int jj = 0; jj < 4; ++jj) acc2[kp][q][jj] = 0.f;

  const float* Wf = W + (size_t)f * H_ * H_;
#pragma unroll
  for (int kp = 0; kp < 2; ++kp) {
    if (kp) __syncthreads();
    for (int p = t; p < 128 * 16; p += 256) {
      const int h = p >> 4, c = p & 15;
      *reinterpret_cast<float4*>(&sW[h][c * 4]) =
          *reinterpret_cast<const float4*>(&Wf[(size_t)h * H_ + kp * 64 + c * 4]);
    }
    __syncthreads();
#pragma unroll 2
    for (int h = 0; h < H_; ++h) {
      const float4 a = *reinterpret_cast<const float4*>(&sW[h][tr * 4]);
      const float4 v = *reinterpret_cast<const float4*>(&sVT[h][tc * 4]);
      acc2[kp][0][0] += a.x * v.x; acc2[kp][0][1] += a.x * v.y; acc2[kp][0][2] += a.x * v.z; acc2[kp][0][3] += a.x * v.w;
      acc2[kp][1][0] += a.y * v.x; acc2[kp][1][1] += a.y * v.y; acc2[kp][1][2] += a.y * v.z; acc2[kp][1][3] += a.y * v.w;
      acc2[kp][2][0] += a.z * v.x; acc2[kp][2][1] += a.z * v.y; acc2[kp][2][2] += a.z * v.z; acc2[kp][2][3] += a.z * v.w;
      acc2[kp][3][0] += a.w * v.x; acc2[kp][3][1] += a.w * v.y; acc2[kp][3][2] += a.w * v.z; acc2[kp][3][3] += a.w * v.w;
    }
  }

  // ---- repack epilogue: scatter f32 into LDS in fragment order ----
  __syncthreads();  // all sW reads done
  float* fl = &sW[0][0];  // 8192 f32 = 32 KB
#pragma unroll
  for (int kp = 0; kp < 2; ++kp)
#pragma unroll
    for (int q = 0; q < 4; ++q)
#pragma unroll
      for (int jj = 0; jj < 4; ++jj) {
        const int k = kp * 64 + tr * 4 + q;
        const int i_loc = tc * 4 + jj;
        const int ks = k >> 5;
        const int ll = (i_loc & 15) + 16 * ((k >> 3) & 3);
        fl[(((tc >> 2) * 4 + ks) << 9) + ll * 8 + (k & 7)] = acc2[kp][q][jj];
      }
  __syncthreads();
  const size_t ufbase = ((size_t)(b * F_ + f) * 192 + it * 16) * 512;
#pragma unroll
  for (int rr = 0; rr < 4; ++rr) {
    const int idx = rr * 2048 + t * 8;
    Pk8 hi, lo;
#pragma unroll
    for (int e = 0; e < 8; ++e) {
      const float v = fl[idx + e];
      const unsigned short h = f2bf(v);
      hi.s[e] = h;
      lo.s[e] = f2bf(v - bf2f(h));
    }
    *reinterpret_cast<uint4*>(UFh + ufbase + idx) = hi.u4;
    *reinterpret_cast<uint4*>(UFl + ufbase + idx) = lo.u4;
  }
}

// ---------------------------------------------------------------------------
// r10_PV: V -> MFMA B-fragment-major bf16 hi/lo.
// frag = (b*48 + jtile)*4 + ks; lane = (j&15)+16*((k>>3)&3), e=k&7.
// grid = 98304/256 = 384.
// ---------------------------------------------------------------------------
__global__ __launch_bounds__(256) void r10_PV(const float* __restrict__ V,
                                              unsigned short* __restrict__ VFh,
                                              unsigned short* __restrict__ VFl) {
  const int task = blockIdx.x * 256 + threadIdx.x;  // < B_*T_*16
  const int b  = task / (T_ * 16);
  const int r  = task % (T_ * 16);
  const int j  = r >> 4;
  const int ko = r & 15;  // k-octet
  const float* src = V + ((size_t)b * T_ + j) * H_ + ko * 8;
  const float4 v0 = *reinterpret_cast<const float4*>(src);
  const float4 v1 = *reinterpret_cast<const float4*>(src + 4);
  const float vv[8] = {v0.x, v0.y, v0.z, v0.w, v1.x, v1.y, v1.z, v1.w};
  Pk8 hi, lo;
#pragma unroll
  for (int e = 0; e < 8; ++e) {
    const unsigned short h = f2bf(vv[e]);
    hi.s[e] = h;
    lo.s[e] = f2bf(vv[e] - bf2f(h));
  }
  const size_t frag = ((size_t)b * 48 + (j >> 4)) * 4 + (ko >> 2);
  const size_t off = frag * 512 + ((size_t)((j & 15) + 16 * (ko & 3))) * 8;
  *reinterpret_cast<uint4*>(VFh + off) = hi.u4;
  *reinterpret_cast<uint4*>(VFl + off) = lo.u4;
}

// ---------------------------------------------------------------------------
// r10_B: S[b][i][j] = max_f U_f V^T via split-bf16 MFMA (hi*hi + hi*lo + lo*hi).
// 256 thr = 4 waves; wave w: 16 i-rows x 64 j. No LDS. grid = 1152.
// ---------------------------------------------------------------------------
__global__ __launch_bounds__(256) void r10_B(const unsigned short* __restrict__ UFh,
                                             const unsigned short* __restrict__ UFl,
                                             const unsigned short* __restrict__ VFh,
                                             const unsigned short* __restrict__ VFl,
                                             float* __restrict__ S) {
  const int blk = blockIdx.x;
  const int jt = blk % (T_ / 64);
  const int it = (blk / (T_ / 64)) % (T_ / 64);
  const int b  = blk / ((T_ / 64) * (T_ / 64));
  const int w  = threadIdx.x >> 6;
  const int l  = threadIdx.x & 63;

  // load B fragments (V) once, keep in registers across f
  short8v Bh[4][4], Bl[4][4];
#pragma unroll
  for (int n = 0; n < 4; ++n)
#pragma unroll
    for (int ks = 0; ks < 4; ++ks) {
      const size_t off =
          (((size_t)b * 48 + jt * 4 + n) * 4 + ks) * 512 + (size_t)l * 8;
      Bh[n][ks] = *reinterpret_cast<const short8v*>(VFh + off);
      Bl[n][ks] = *reinterpret_cast<const short8v*>(VFl + off);
    }

  f32x4 smax[4];
#pragma unroll
  for (int n = 0; n < 4; ++n)
#pragma unroll
    for (int q = 0; q < 4; ++q) smax[n][q] = -3.4e38f;

  for (int f = 0; f < F_; ++f) {
    const size_t abase = ((size_t)(b * F_ + f) * 48 + it * 4 + w) * 4;
    short8v Ah[4], Al[4];
#pragma unroll
    for (int ks = 0; ks < 4; ++ks) {
      const size_t off = (abase + ks) * 512 + (size_t)l * 8;
      Ah[ks] = *reinterpret_cast<const short8v*>(UFh + off);
      Al[ks] = *reinterpret_cast<const short8v*>(UFl + off);
    }
    f32x4 acc[4];
#pragma unroll
    for (int n = 0; n < 4; ++n)
#pragma unroll
      for (int q = 0; q < 4; ++q) acc[n][q] = 0.f;
#pragma unroll
    for (int ks = 0; ks < 4; ++ks)
#pragma unroll
      for (int n = 0; n < 4; ++n) {
        acc[n] = __builtin_amdgcn_mfma_f32_16x16x32_bf16(Ah[ks], Bh[n][ks], acc[n], 0, 0, 0);
        acc[n] = __builtin_amdgcn_mfma_f32_16x16x32_bf16(Al[ks], Bh[n][ks], acc[n], 0, 0, 0);
        acc[n] = __builtin_amdgcn_mfma_f32_16x16x32_bf16(Ah[ks], Bl[n][ks], acc[n], 0, 0, 0);
      }
#pragma unroll
    for (int n = 0; n < 4; ++n)
#pragma unroll
      for (int q = 0; q < 4; ++q) smax[n][q] = fmaxf(smax[n][q], acc[n][q]);
  }

  // C/D layout (m89-verified): col = l&15, row = (l>>4)*4 + q
  const int i0 = it * 64 + w * 16 + (l >> 4) * 4;
  const int j0 = jt * 64 + (l & 15);
#pragma unroll
  for (int n = 0; n < 4; ++n)
#pragma unroll
    for (int q = 0; q < 4; ++q)
      S[((size_t)b * T_ + i0 + q) * T_ + j0 + n * 16] = smax[n][q];
}

// ---------------------------------------------------------------------------
// r9_C: row softmax of S, then O = P @ V  (unchanged, verified)
// ---------------------------------------------------------------------------
__global__ __launch_bounds__(256) void r9_C(const float* __restrict__ V,
                                            const float* __restrict__ S,
                                            float* __restrict__ O) {
  __shared__ __align__(16) float sP[16][772];
  const int blk = blockIdx.x;
  const int it = blk % (T_ / 16);
  const int b  = blk / (T_ / 16);
  const int t  = threadIdx.x;
  const int r  = t >> 4;
  const int c  = t & 15;

  const float* Srow = S + (size_t)(b * T_ + it * 16) * T_;

  float4 buf[12];
  float m = -3.4e38f;
#pragma unroll
  for (int q = 0; q < 12; ++q) {
    const int j4 = c + q * 16;
    const float4 x = *reinterpret_cast<const float4*>(&Srow[r * T_ + j4 * 4]);
    buf[q] = x;
    m = fmaxf(m, fmaxf(fmaxf(x.x, x.y), fmaxf(x.z, x.w)));
  }
  m = fmaxf(m, __shfl_xor(m, 1));
  m = fmaxf(m, __shfl_xor(m, 2));
  m = fmaxf(m, __shfl_xor(m, 4));
  m = fmaxf(m, __shfl_xor(m, 8));

  float l = 0.f;
#pragma unroll
  for (int q = 0; q < 12; ++q) {
    const int j4 = c + q * 16;
    float4 e;
    e.x = expf(buf[q].x - m);
    e.y = expf(buf[q].y - m);
    e.z = expf(buf[q].z - m);
    e.w = expf(buf[q].w - m);
    l += (e.x + e.y) + (e.z + e.w);
    *reinterpret_cast<float4*>(&sP[r][j4 * 4]) = e;
  }
  l += __shfl_xor(l, 1);
  l += __shfl_xor(l, 2);
  l += __shfl_xor(l, 4);
  l += __shfl_xor(l, 8);
  __syncthreads();

  const float inv = 1.0f / l;
  float acc[8] = {};
  const float* Vb = V + (size_t)b * T_ * H_ + c * 8;
#pragma unroll 8
  for (int j = 0; j < T_; ++j) {
    const float p = sP[r][j];
    const float4 v0 = *reinterpret_cast<const float4*>(&Vb[(size_t)j * H_]);
    const float4 v1 = *reinterpret_cast<const float4*>(&Vb[(size_t)j * H_ + 4]);
    acc[0] += p * v0.x; acc[1] += p * v0.y; acc[2] += p * v0.z; acc[3] += p * v0.w;
    acc[4] += p * v1.x; acc[5] += p * v1.y; acc[6] += p * v1.z; acc[7] += p * v1.w;
  }
  float4 o0 = make_float4(acc[0] * inv, acc[1] * inv, acc[2] * inv, acc[3] * inv);
  float4 o1 = make_float4(acc[4] * inv, acc[5] * inv, acc[6] * inv, acc[7] * inv);
  float* Orow = O + (size_t)(b * T_ + it * 16 + r) * H_ + c * 8;
  *reinterpret_cast<float4*>(&Orow[0]) = o0;
  *reinterpret_cast<float4*>(&Orow[4]) = o1;
}

// ---------------------------------------------------------------------------
extern "C" void kernel_launch(void* const* d_in, const int* in_sizes, int n_in,
                              void* d_out, int out_size, void* d_ws, size_t ws_size,
                              hipStream_t stream) {
  const float* V = (const float*)d_in[0];  // f32 [B,T,H]
  const float* W = (const float*)d_in[1];  // f32 [F,H,H]
  if (n_in >= 2 && in_sizes[0] == F_ * H_ * H_) {
    V = (const float*)d_in[1];
    W = (const float*)d_in[0];
  }
  float* O = (float*)d_out;  // f32 [B,T,H]

  const size_t s_bytes  = (size_t)B_ * T_ * T_ * 4;       // 18,874,368
  const size_t uf_bytes = (size_t)B_ * F_ * H_ * T_ * 2;  // 15,728,640
  const size_t vf_bytes = (size_t)B_ * H_ * T_ * 2;       //  1,572,864
  const size_t need = s_bytes + 2 * uf_bytes + 2 * vf_bytes;  // 53,477,376
  if (ws_size < need) return;

  char* base = (char*)d_ws;
  float* S  = (float*)base;       // [B,T,T]
  float* VT = (float*)base;       // overlaid: dead before S is written
  unsigned short* UFh = (unsigned short*)(base + s_bytes);
  unsigned short* UFl = (unsigned short*)(base + s_bytes + uf_bytes);
  unsigned short* VFh = (unsigned short*)(base + s_bytes + 2 * uf_bytes);
  unsigned short* VFl = (unsigned short*)(base + s_bytes + 2 * uf_bytes + vf_bytes);

  r9_T<<<B_ * (T_ / 32) * (H_ / 32), 256, 0, stream>>>(V, VT);
  r10_A<<<B_ * F_ * (T_ / 64), 256, 0, stream>>>(VT, W, UFh, UFl);
  r10_PV<<<B_ * T_ * 16 / 256, 256, 0, stream>>>(V, VFh, VFl);
  r10_B<<<B_ * (T_ / 64) * (T_ / 64), 256, 0, stream>>>(UFh, UFl, VFh, VFl, S);
  r9_C<<<B_ * (T_ / 16), 256, 0, stream>>>(V, S, O);
}

// Round 11
// 116.558 us; speedup vs baseline: 2.9793x; 1.6151x over previous
//
#include <hip/hip_runtime.h>
#include <hip/hip_bf16.h>

#define B_ 8
#define T_ 768
#define H_ 128
#define F_ 10

using short8v = __attribute__((ext_vector_type(8))) short;
using f32x4   = __attribute__((ext_vector_type(4))) float;

__device__ __forceinline__ float bf2f(unsigned short s) {
  union { unsigned int u; float f; } w;
  w.u = ((unsigned int)s) << 16;
  return w.f;
}
__device__ __forceinline__ unsigned short f2bf(float x) {
  __hip_bfloat16 h = __float2bfloat16(x);  // RN
  return *reinterpret_cast<unsigned short*>(&h);
}
union Pk8 { uint4 u4; unsigned short s[8]; };

// ---------------------------------------------------------------------------
// r9_T: VT[b][h][j] = V[b][j][h]  (verified)
// ---------------------------------------------------------------------------
__global__ __launch_bounds__(256) void r9_T(const float* __restrict__ V,
                                            float* __restrict__ VT) {
  __shared__ float tile[32][33];
  const int blk = blockIdx.x;
  const int ht = blk % (H_ / 32);
  const int it = (blk / (H_ / 32)) % (T_ / 32);
  const int b  = blk / ((H_ / 32) * (T_ / 32));
  const int tx = threadIdx.x & 31;
  const int ty = threadIdx.x >> 5;

  const float* Vb = V + (size_t)b * T_ * H_;
#pragma unroll
  for (int r = ty; r < 32; r += 8)
    tile[r][tx] = Vb[(size_t)(it * 32 + r) * H_ + ht * 32 + tx];
  __syncthreads();
  float* VTb = VT + (size_t)b * H_ * T_;
#pragma unroll
  for (int r = ty; r < 32; r += 8)
    VTb[(size_t)(ht * 32 + r) * T_ + it * 32 + tx] = tile[tx][r];
}

// ---------------------------------------------------------------------------
// r10_A: U in f32, written as MFMA A-fragment-major bf16 hi/lo (verified)
// ---------------------------------------------------------------------------
__global__ __launch_bounds__(256) void r10_A(const float* __restrict__ VT,
                                             const float* __restrict__ W,
                                             unsigned short* __restrict__ UFh,
                                             unsigned short* __restrict__ UFl) {
  __shared__ __align__(16) float sW[128][64];
  __shared__ __align__(16) float sVT[128][64];
  const int blk = blockIdx.x;
  const int it = blk % (T_ / 64);
  const int f  = (blk / (T_ / 64)) % F_;
  const int b  = blk / ((T_ / 64) * F_);
  const int t  = threadIdx.x;
  const int tr = t >> 4;
  const int tc = t & 15;

  {
    const float* VTb = VT + (size_t)b * H_ * T_ + it * 64;
    for (int p = t; p < 128 * 16; p += 256) {
      const int h = p >> 4, c = p & 15;
      *reinterpret_cast<float4*>(&sVT[h][c * 4]) =
          *reinterpret_cast<const float4*>(&VTb[(size_t)h * T_ + c * 4]);
    }
  }

  float acc2[2][4][4];
#pragma unroll
  for (int kp = 0; kp < 2; ++kp)
#pragma unroll
    for (int q = 0; q < 4; ++q)
#pragma unroll
      for (int jj = 0; jj < 4; ++jj) acc2[kp][q][jj] = 0.f;

  const float* Wf = W + (size_t)f * H_ * H_;
#pragma unroll
  for (int kp = 0; kp < 2; ++kp) {
    if (kp) __syncthreads();
    for (int p = t; p < 128 * 16; p += 256) {
      const int h = p >> 4, c = p & 15;
      *reinterpret_cast<float4*>(&sW[h][c * 4]) =
          *reinterpret_cast<const float4*>(&Wf[(size_t)h * H_ + kp * 64 + c * 4]);
    }
    __syncthreads();
#pragma unroll 2
    for (int h = 0; h < H_; ++h) {
      const float4 a = *reinterpret_cast<const float4*>(&sW[h][tr * 4]);
      const float4 v = *reinterpret_cast<const float4*>(&sVT[h][tc * 4]);
      acc2[kp][0][0] += a.x * v.x; acc2[kp][0][1] += a.x * v.y; acc2[kp][0][2] += a.x * v.z; acc2[kp][0][3] += a.x * v.w;
      acc2[kp][1][0] += a.y * v.x; acc2[kp][1][1] += a.y * v.y; acc2[kp][1][2] += a.y * v.z; acc2[kp][1][3] += a.y * v.w;
      acc2[kp][2][0] += a.z * v.x; acc2[kp][2][1] += a.z * v.y; acc2[kp][2][2] += a.z * v.z; acc2[kp][2][3] += a.z * v.w;
      acc2[kp][3][0] += a.w * v.x; acc2[kp][3][1] += a.w * v.y; acc2[kp][3][2] += a.w * v.z; acc2[kp][3][3] += a.w * v.w;
    }
  }

  __syncthreads();
  float* fl = &sW[0][0];
#pragma unroll
  for (int kp = 0; kp < 2; ++kp)
#pragma unroll
    for (int q = 0; q < 4; ++q)
#pragma unroll
      for (int jj = 0; jj < 4; ++jj) {
        const int k = kp * 64 + tr * 4 + q;
        const int i_loc = tc * 4 + jj;
        const int ks = k >> 5;
        const int ll = (i_loc & 15) + 16 * ((k >> 3) & 3);
        fl[(((tc >> 2) * 4 + ks) << 9) + ll * 8 + (k & 7)] = acc2[kp][q][jj];
      }
  __syncthreads();
  const size_t ufbase = ((size_t)(b * F_ + f) * 192 + it * 16) * 512;
#pragma unroll
  for (int rr = 0; rr < 4; ++rr) {
    const int idx = rr * 2048 + t * 8;
    Pk8 hi, lo;
#pragma unroll
    for (int e = 0; e < 8; ++e) {
      const float v = fl[idx + e];
      const unsigned short h = f2bf(v);
      hi.s[e] = h;
      lo.s[e] = f2bf(v - bf2f(h));
    }
    *reinterpret_cast<uint4*>(UFh + ufbase + idx) = hi.u4;
    *reinterpret_cast<uint4*>(UFl + ufbase + idx) = lo.u4;
  }
}

// ---------------------------------------------------------------------------
// r10_PV: V -> scores-B fragments (k = H dim)  (verified)
// ---------------------------------------------------------------------------
__global__ __launch_bounds__(256) void r10_PV(const float* __restrict__ V,
                                              unsigned short* __restrict__ VFh,
                                              unsigned short* __restrict__ VFl) {
  const int task = blockIdx.x * 256 + threadIdx.x;
  const int b  = task / (T_ * 16);
  const int r  = task % (T_ * 16);
  const int j  = r >> 4;
  const int ko = r & 15;
  const float* src = V + ((size_t)b * T_ + j) * H_ + ko * 8;
  const float4 v0 = *reinterpret_cast<const float4*>(src);
  const float4 v1 = *reinterpret_cast<const float4*>(src + 4);
  const float vv[8] = {v0.x, v0.y, v0.z, v0.w, v1.x, v1.y, v1.z, v1.w};
  Pk8 hi, lo;
#pragma unroll
  for (int e = 0; e < 8; ++e) {
    const unsigned short h = f2bf(vv[e]);
    hi.s[e] = h;
    lo.s[e] = f2bf(vv[e] - bf2f(h));
  }
  const size_t frag = ((size_t)b * 48 + (j >> 4)) * 4 + (ko >> 2);
  const size_t off = frag * 512 + ((size_t)((j & 15) + 16 * (ko & 3))) * 8;
  *reinterpret_cast<uint4*>(VFh + off) = hi.u4;
  *reinterpret_cast<uint4*>(VFl + off) = lo.u4;
}

// ---------------------------------------------------------------------------
// r10_B: S = max_f U_f V^T via split-bf16 MFMA  (verified)
// ---------------------------------------------------------------------------
__global__ __launch_bounds__(256) void r10_B(const unsigned short* __restrict__ UFh,
                                             const unsigned short* __restrict__ UFl,
                                             const unsigned short* __restrict__ VFh,
                                             const unsigned short* __restrict__ VFl,
                                             float* __restrict__ S) {
  const int blk = blockIdx.x;
  const int jt = blk % (T_ / 64);
  const int it = (blk / (T_ / 64)) % (T_ / 64);
  const int b  = blk / ((T_ / 64) * (T_ / 64));
  const int w  = threadIdx.x >> 6;
  const int l  = threadIdx.x & 63;

  short8v Bh[4][4], Bl[4][4];
#pragma unroll
  for (int n = 0; n < 4; ++n)
#pragma unroll
    for (int ks = 0; ks < 4; ++ks) {
      const size_t off =
          (((size_t)b * 48 + jt * 4 + n) * 4 + ks) * 512 + (size_t)l * 8;
      Bh[n][ks] = *reinterpret_cast<const short8v*>(VFh + off);
      Bl[n][ks] = *reinterpret_cast<const short8v*>(VFl + off);
    }

  f32x4 smax[4];
#pragma unroll
  for (int n = 0; n < 4; ++n)
#pragma unroll
    for (int q = 0; q < 4; ++q) smax[n][q] = -3.4e38f;

  for (int f = 0; f < F_; ++f) {
    const size_t abase = ((size_t)(b * F_ + f) * 48 + it * 4 + w) * 4;
    short8v Ah[4], Al[4];
#pragma unroll
    for (int ks = 0; ks < 4; ++ks) {
      const size_t off = (abase + ks) * 512 + (size_t)l * 8;
      Ah[ks] = *reinterpret_cast<const short8v*>(UFh + off);
      Al[ks] = *reinterpret_cast<const short8v*>(UFl + off);
    }
    f32x4 acc[4];
#pragma unroll
    for (int n = 0; n < 4; ++n)
#pragma unroll
      for (int q = 0; q < 4; ++q) acc[n][q] = 0.f;
#pragma unroll
    for (int ks = 0; ks < 4; ++ks)
#pragma unroll
      for (int n = 0; n < 4; ++n) {
        acc[n] = __builtin_amdgcn_mfma_f32_16x16x32_bf16(Ah[ks], Bh[n][ks], acc[n], 0, 0, 0);
        acc[n] = __builtin_amdgcn_mfma_f32_16x16x32_bf16(Al[ks], Bh[n][ks], acc[n], 0, 0, 0);
        acc[n] = __builtin_amdgcn_mfma_f32_16x16x32_bf16(Ah[ks], Bl[n][ks], acc[n], 0, 0, 0);
      }
#pragma unroll
    for (int n = 0; n < 4; ++n)
#pragma unroll
      for (int q = 0; q < 4; ++q) smax[n][q] = fmaxf(smax[n][q], acc[n][q]);
  }

  const int i0 = it * 64 + w * 16 + (l >> 4) * 4;
  const int j0 = jt * 64 + (l & 15);
#pragma unroll
  for (int n = 0; n < 4; ++n)
#pragma unroll
    for (int q = 0; q < 4; ++q)
      S[((size_t)b * T_ + i0 + q) * T_ + j0 + n * 16] = smax[n][q];
}

// ---------------------------------------------------------------------------
// r11_PW: V -> PV-B fragments (j as K dim, h as N dim), hi/lo.
// frag = ((b*8 + ht)*24 + ks); lane = (h&15) + 16*((j>>3)&3), e = j&7.
// thread = (b, j-octet, h). grid = 8*96*128/256 = 384.
// Runs AFTER r10_B: writes into the dead UF region.
// ---------------------------------------------------------------------------
__global__ __launch_bounds__(256) void r11_PW(const float* __restrict__ V,
                                              unsigned short* __restrict__ VPh,
                                              unsigned short* __restrict__ VPl) {
  const int tid = blockIdx.x * 256 + threadIdx.x;  // < 98304
  const int h    = tid & 127;
  const int rest = tid >> 7;
  const int jo   = rest % 96;
  const int b    = rest / 96;
  const int j0   = jo * 8;

  Pk8 hi, lo;
#pragma unroll
  for (int e = 0; e < 8; ++e) {
    const float v = V[((size_t)b * T_ + j0 + e) * H_ + h];
    const unsigned short hh = f2bf(v);
    hi.s[e] = hh;
    lo.s[e] = f2bf(v - bf2f(hh));
  }
  const size_t frag = ((size_t)b * 8 + (h >> 4)) * 24 + (j0 >> 5);
  const size_t off = frag * 512 + ((size_t)((h & 15) + 16 * ((j0 >> 3) & 3))) * 8;
  *reinterpret_cast<uint4*>(VPh + off) = hi.u4;
  *reinterpret_cast<uint4*>(VPl + off) = lo.u4;
}

// ---------------------------------------------------------------------------
// r11_C: softmax (verified r9_C pattern) -> P bf16 in LDS -> PV via MFMA.
// Block = (b, 16-row i-tile), 256 thr = 4 waves; wave w covers h = w*32..+31.
// grid = 8*48 = 384.
// ---------------------------------------------------------------------------
__global__ __launch_bounds__(256) void r11_C(const unsigned short* __restrict__ VPh,
                                             const unsigned short* __restrict__ VPl,
                                             const float* __restrict__ S,
                                             float* __restrict__ O) {
  __shared__ __align__(16) unsigned short sP[16][776];  // bf16 P, padded row
  __shared__ float sInv[16];
  const int blk = blockIdx.x;
  const int it = blk % (T_ / 16);
  const int b  = blk / (T_ / 16);
  const int t  = threadIdx.x;
  const int r  = t >> 4;   // row 0..15
  const int c  = t & 15;   // lane-in-row

  const float* Srow = S + (size_t)(b * T_ + it * 16) * T_;

  float4 buf[12];
  float m = -3.4e38f;
#pragma unroll
  for (int q = 0; q < 12; ++q) {
    const int j4 = c + q * 16;
    const float4 x = *reinterpret_cast<const float4*>(&Srow[r * T_ + j4 * 4]);
    buf[q] = x;
    m = fmaxf(m, fmaxf(fmaxf(x.x, x.y), fmaxf(x.z, x.w)));
  }
  m = fmaxf(m, __shfl_xor(m, 1));
  m = fmaxf(m, __shfl_xor(m, 2));
  m = fmaxf(m, __shfl_xor(m, 4));
  m = fmaxf(m, __shfl_xor(m, 8));

  float l = 0.f;
#pragma unroll
  for (int q = 0; q < 12; ++q) {
    const int j4 = c + q * 16;
    float4 e;
    e.x = expf(buf[q].x - m);
    e.y = expf(buf[q].y - m);
    e.z = expf(buf[q].z - m);
    e.w = expf(buf[q].w - m);
    l += (e.x + e.y) + (e.z + e.w);
    ushort4 pb;
    pb.x = f2bf(e.x); pb.y = f2bf(e.y); pb.z = f2bf(e.z); pb.w = f2bf(e.w);
    *reinterpret_cast<ushort4*>(&sP[r][j4 * 4]) = pb;
  }
  l += __shfl_xor(l, 1);
  l += __shfl_xor(l, 2);
  l += __shfl_xor(l, 4);
  l += __shfl_xor(l, 8);
  if (c == 0) sInv[r] = 1.0f / l;
  __syncthreads();

  // PV: rows 0-15 (one m-frag), wave w covers n-frags ht = 2w, 2w+1.
  const int w  = t >> 6;
  const int lv = t & 63;
  f32x4 acc0, acc1;
#pragma unroll
  for (int q = 0; q < 4; ++q) { acc0[q] = 0.f; acc1[q] = 0.f; }

  const int arow = lv & 15;
  const int koct = lv >> 4;  // 0..3
#pragma unroll
  for (int ks = 0; ks < 24; ++ks) {
    const short8v pa =
        *reinterpret_cast<const short8v*>(&sP[arow][ks * 32 + koct * 8]);
    const size_t f0 = (((size_t)b * 8 + (w * 2 + 0)) * 24 + ks) * 512 + (size_t)lv * 8;
    const size_t f1 = (((size_t)b * 8 + (w * 2 + 1)) * 24 + ks) * 512 + (size_t)lv * 8;
    const short8v b0h = *reinterpret_cast<const short8v*>(VPh + f0);
    const short8v b0l = *reinterpret_cast<const short8v*>(VPl + f0);
    const short8v b1h = *reinterpret_cast<const short8v*>(VPh + f1);
    const short8v b1l = *reinterpret_cast<const short8v*>(VPl + f1);
    acc0 = __builtin_amdgcn_mfma_f32_16x16x32_bf16(pa, b0h, acc0, 0, 0, 0);
    acc0 = __builtin_amdgcn_mfma_f32_16x16x32_bf16(pa, b0l, acc0, 0, 0, 0);
    acc1 = __builtin_amdgcn_mfma_f32_16x16x32_bf16(pa, b1h, acc1, 0, 0, 0);
    acc1 = __builtin_amdgcn_mfma_f32_16x16x32_bf16(pa, b1l, acc1, 0, 0, 0);
  }

  // C/D: col = lv&15 (h within ht), row = (lv>>4)*4 + q (i within tile)
  const int hcol = lv & 15;
#pragma unroll
  for (int q = 0; q < 4; ++q) {
    const int irow = (lv >> 4) * 4 + q;
    const float inv = sInv[irow];
    const size_t obase = ((size_t)(b * T_ + it * 16 + irow)) * H_;
    O[obase + (w * 2 + 0) * 16 + hcol] = acc0[q] * inv;
    O[obase + (w * 2 + 1) * 16 + hcol] = acc1[q] * inv;
  }
}

// ---------------------------------------------------------------------------
extern "C" void kernel_launch(void* const* d_in, const int* in_sizes, int n_in,
                              void* d_out, int out_size, void* d_ws, size_t ws_size,
                              hipStream_t stream) {
  const float* V = (const float*)d_in[0];  // f32 [B,T,H]
  const float* W = (const float*)d_in[1];  // f32 [F,H,H]
  if (n_in >= 2 && in_sizes[0] == F_ * H_ * H_) {
    V = (const float*)d_in[1];
    W = (const float*)d_in[0];
  }
  float* O = (float*)d_out;  // f32 [B,T,H]

  const size_t s_bytes  = (size_t)B_ * T_ * T_ * 4;       // 18,874,368
  const size_t uf_bytes = (size_t)B_ * F_ * H_ * T_ * 2;  // 15,728,640
  const size_t vf_bytes = (size_t)B_ * H_ * T_ * 2;       //  1,572,864
  const size_t need = s_bytes + 2 * uf_bytes + 2 * vf_bytes;  // 53,477,376
  if (ws_size < need) return;

  char* base = (char*)d_ws;
  float* S  = (float*)base;   // [B,T,T]
  float* VT = (float*)base;   // overlaid: dead before S written
  unsigned short* UFh = (unsigned short*)(base + s_bytes);
  unsigned short* UFl = (unsigned short*)(base + s_bytes + uf_bytes);
  unsigned short* VFh = (unsigned short*)(base + s_bytes + 2 * uf_bytes);
  unsigned short* VFl = (unsigned short*)(base + s_bytes + 2 * uf_bytes + vf_bytes);
  // VP overlays UF: written by r11_PW only after r10_B (UF's last reader).
  unsigned short* VPh = UFh;
  unsigned short* VPl = UFh + vf_bytes / 2;

  r9_T<<<B_ * (T_ / 32) * (H_ / 32), 256, 0, stream>>>(V, VT);
  r10_A<<<B_ * F_ * (T_ / 64), 256, 0, stream>>>(VT, W, UFh, UFl);
  r10_PV<<<B_ * T_ * 16 / 256, 256, 0, stream>>>(V, VFh, VFl);
  r10_B<<<B_ * (T_ / 64) * (T_ / 64), 256, 0, stream>>>(UFh, UFl, VFh, VFl, S);
  r11_PW<<<B_ * 96 * 128 / 256, 256, 0, stream>>>(V, VPh, VPl);
  r11_C<<<B_ * (T_ / 16), 256, 0, stream>>>(VPh, VPl, S, O);
}

// Round 12
// 91.151 us; speedup vs baseline: 3.8097x; 1.2787x over previous
//
#include <hip/hip_runtime.h>
#include <hip/hip_bf16.h>

#define B_ 8
#define T_ 768
#define H_ 128
#define F_ 10

using short8v = __attribute__((ext_vector_type(8))) short;
using f32x4   = __attribute__((ext_vector_type(4))) float;

__device__ __forceinline__ float bf2f(unsigned short s) {
  union { unsigned int u; float f; } w;
  w.u = ((unsigned int)s) << 16;
  return w.f;
}
__device__ __forceinline__ unsigned short f2bf(float x) {
  __hip_bfloat16 h = __float2bfloat16(x);  // RN
  return *reinterpret_cast<unsigned short*>(&h);
}
union Pk8 { uint4 u4; unsigned short s[8]; };

// ---------------------------------------------------------------------------
// r10_PV: V -> row-major fragments (rows = T index, K = H dim), hi/lo.
// frag = (b*48 + (j>>4))*4 + ks; lane = (j&15)+16*((k>>3)&3); e = k&7.
// Used as B-operand in r10_B AND as A-operand in r12_A (same convention,
// verified end-to-end in round 10).  grid = 384.
// ---------------------------------------------------------------------------
__global__ __launch_bounds__(256) void r10_PV(const float* __restrict__ V,
                                              unsigned short* __restrict__ VFh,
                                              unsigned short* __restrict__ VFl) {
  const int task = blockIdx.x * 256 + threadIdx.x;
  const int b  = task / (T_ * 16);
  const int r  = task % (T_ * 16);
  const int j  = r >> 4;
  const int ko = r & 15;
  const float* src = V + ((size_t)b * T_ + j) * H_ + ko * 8;
  const float4 v0 = *reinterpret_cast<const float4*>(src);
  const float4 v1 = *reinterpret_cast<const float4*>(src + 4);
  const float vv[8] = {v0.x, v0.y, v0.z, v0.w, v1.x, v1.y, v1.z, v1.w};
  Pk8 hi, lo;
#pragma unroll
  for (int e = 0; e < 8; ++e) {
    const unsigned short h = f2bf(vv[e]);
    hi.s[e] = h;
    lo.s[e] = f2bf(vv[e] - bf2f(h));
  }
  const size_t frag = ((size_t)b * 48 + (j >> 4)) * 4 + (ko >> 2);
  const size_t off = frag * 512 + ((size_t)((j & 15) + 16 * (ko & 3))) * 8;
  *reinterpret_cast<uint4*>(VFh + off) = hi.u4;
  *reinterpret_cast<uint4*>(VFl + off) = lo.u4;
}

// ---------------------------------------------------------------------------
// r12_PW2: W[f][h][k] -> B-operand fragments (K = h, N = k), hi/lo.
// frag = (f*8 + n)*4 + ks; lane = (k&15)+16*((h>>3)&3); e = h&7.
// 20480 threads = 80 blocks. W is 0.65 MB -> L2; scalar reads fine.
// ---------------------------------------------------------------------------
__global__ __launch_bounds__(256) void r12_PW2(const float* __restrict__ W,
                                               unsigned short* __restrict__ WFh,
                                               unsigned short* __restrict__ WFl) {
  const int tid = blockIdx.x * 256 + threadIdx.x;  // < 320*64
  const int frag = tid >> 6;
  const int l    = tid & 63;
  const int f    = frag >> 5;
  const int rest = frag & 31;
  const int n    = rest >> 2;
  const int ks   = rest & 3;
  const int k  = n * 16 + (l & 15);
  const int h0 = ks * 32 + ((l >> 4) * 8);
  Pk8 hi, lo;
#pragma unroll
  for (int e = 0; e < 8; ++e) {
    const float v = W[((size_t)f * H_ + h0 + e) * H_ + k];
    const unsigned short hh = f2bf(v);
    hi.s[e] = hh;
    lo.s[e] = f2bf(v - bf2f(hh));
  }
  const size_t off = (size_t)frag * 512 + (size_t)l * 8;
  *reinterpret_cast<uint4*>(WFh + off) = hi.u4;
  *reinterpret_cast<uint4*>(WFl + off) = lo.u4;
}

// ---------------------------------------------------------------------------
// r12_A: U[b][f] = V_b @ W_f via split-bf16 MFMA; output repacked through LDS
// into UF A-fragment layout (same epilogue convention as verified r10_A).
// Block = (b, f, 64-i tile), 4 waves; wave w = m-frag it*4+w, all 8 n-frags.
// grid = 8*10*12 = 960. LDS 32 KB.
// ---------------------------------------------------------------------------
__global__ __launch_bounds__(256) void r12_A(const unsigned short* __restrict__ VFh,
                                             const unsigned short* __restrict__ VFl,
                                             const unsigned short* __restrict__ WFh,
                                             const unsigned short* __restrict__ WFl,
                                             unsigned short* __restrict__ UFh,
                                             unsigned short* __restrict__ UFl) {
  __shared__ __align__(16) float fl[8192];
  const int blk = blockIdx.x;
  const int it = blk % (T_ / 64);
  const int f  = (blk / (T_ / 64)) % F_;
  const int b  = blk / ((T_ / 64) * F_);
  const int t  = threadIdx.x;
  const int w  = t >> 6;
  const int l  = t & 63;

  short8v Ah[4], Al[4];
#pragma unroll
  for (int ks = 0; ks < 4; ++ks) {
    const size_t off = (((size_t)b * 48 + it * 4 + w) * 4 + ks) * 512 + (size_t)l * 8;
    Ah[ks] = *reinterpret_cast<const short8v*>(VFh + off);
    Al[ks] = *reinterpret_cast<const short8v*>(VFl + off);
  }

  f32x4 acc[8];
#pragma unroll
  for (int n = 0; n < 8; ++n)
#pragma unroll
    for (int q = 0; q < 4; ++q) acc[n][q] = 0.f;

#pragma unroll
  for (int n = 0; n < 8; ++n)
#pragma unroll
    for (int ks = 0; ks < 4; ++ks) {
      const size_t off = ((size_t)(f * 8 + n) * 4 + ks) * 512 + (size_t)l * 8;
      const short8v bh = *reinterpret_cast<const short8v*>(WFh + off);
      const short8v bl = *reinterpret_cast<const short8v*>(WFl + off);
      acc[n] = __builtin_amdgcn_mfma_f32_16x16x32_bf16(Ah[ks], bh, acc[n], 0, 0, 0);
      acc[n] = __builtin_amdgcn_mfma_f32_16x16x32_bf16(Al[ks], bh, acc[n], 0, 0, 0);
      acc[n] = __builtin_amdgcn_mfma_f32_16x16x32_bf16(Ah[ks], bl, acc[n], 0, 0, 0);
    }

  // scatter D (i = w*16+(l>>4)*4+q, k = n*16+(l&15)) into UF-frag order
#pragma unroll
  for (int n = 0; n < 8; ++n)
#pragma unroll
    for (int q = 0; q < 4; ++q) {
      const int i_loc = w * 16 + (l >> 4) * 4 + q;
      const int k = n * 16 + (l & 15);
      const int ll = (i_loc & 15) + 16 * ((k >> 3) & 3);
      fl[((w * 4 + (k >> 5)) << 9) + ll * 8 + (k & 7)] = acc[n][q];
    }
  __syncthreads();
  const size_t ufbase = ((size_t)(b * F_ + f) * 192 + it * 16) * 512;
#pragma unroll
  for (int rr = 0; rr < 4; ++rr) {
    const int idx = rr * 2048 + t * 8;
    const float4 v0 = *reinterpret_cast<const float4*>(&fl[idx]);
    const float4 v1 = *reinterpret_cast<const float4*>(&fl[idx + 4]);
    const float vv[8] = {v0.x, v0.y, v0.z, v0.w, v1.x, v1.y, v1.z, v1.w};
    Pk8 hi, lo;
#pragma unroll
    for (int e = 0; e < 8; ++e) {
      const unsigned short h = f2bf(vv[e]);
      hi.s[e] = h;
      lo.s[e] = f2bf(vv[e] - bf2f(h));
    }
    *reinterpret_cast<uint4*>(UFh + ufbase + idx) = hi.u4;
    *reinterpret_cast<uint4*>(UFl + ufbase + idx) = lo.u4;
  }
}

// ---------------------------------------------------------------------------
// r10_B: S = max_f U_f V^T via split-bf16 MFMA  (verified)
// ---------------------------------------------------------------------------
__global__ __launch_bounds__(256) void r10_B(const unsigned short* __restrict__ UFh,
                                             const unsigned short* __restrict__ UFl,
                                             const unsigned short* __restrict__ VFh,
                                             const unsigned short* __restrict__ VFl,
                                             float* __restrict__ S) {
  const int blk = blockIdx.x;
  const int jt = blk % (T_ / 64);
  const int it = (blk / (T_ / 64)) % (T_ / 64);
  const int b  = blk / ((T_ / 64) * (T_ / 64));
  const int w  = threadIdx.x >> 6;
  const int l  = threadIdx.x & 63;

  short8v Bh[4][4], Bl[4][4];
#pragma unroll
  for (int n = 0; n < 4; ++n)
#pragma unroll
    for (int ks = 0; ks < 4; ++ks) {
      const size_t off =
          (((size_t)b * 48 + jt * 4 + n) * 4 + ks) * 512 + (size_t)l * 8;
      Bh[n][ks] = *reinterpret_cast<const short8v*>(VFh + off);
      Bl[n][ks] = *reinterpret_cast<const short8v*>(VFl + off);
    }

  f32x4 smax[4];
#pragma unroll
  for (int n = 0; n < 4; ++n)
#pragma unroll
    for (int q = 0; q < 4; ++q) smax[n][q] = -3.4e38f;

  for (int f = 0; f < F_; ++f) {
    const size_t abase = ((size_t)(b * F_ + f) * 48 + it * 4 + w) * 4;
    short8v Ah[4], Al[4];
#pragma unroll
    for (int ks = 0; ks < 4; ++ks) {
      const size_t off = (abase + ks) * 512 + (size_t)l * 8;
      Ah[ks] = *reinterpret_cast<const short8v*>(UFh + off);
      Al[ks] = *reinterpret_cast<const short8v*>(UFl + off);
    }
    f32x4 acc[4];
#pragma unroll
    for (int n = 0; n < 4; ++n)
#pragma unroll
      for (int q = 0; q < 4; ++q) acc[n][q] = 0.f;
#pragma unroll
    for (int ks = 0; ks < 4; ++ks)
#pragma unroll
      for (int n = 0; n < 4; ++n) {
        acc[n] = __builtin_amdgcn_mfma_f32_16x16x32_bf16(Ah[ks], Bh[n][ks], acc[n], 0, 0, 0);
        acc[n] = __builtin_amdgcn_mfma_f32_16x16x32_bf16(Al[ks], Bh[n][ks], acc[n], 0, 0, 0);
        acc[n] = __builtin_amdgcn_mfma_f32_16x16x32_bf16(Ah[ks], Bl[n][ks], acc[n], 0, 0, 0);
      }
#pragma unroll
    for (int n = 0; n < 4; ++n)
#pragma unroll
      for (int q = 0; q < 4; ++q) smax[n][q] = fmaxf(smax[n][q], acc[n][q]);
  }

  const int i0 = it * 64 + w * 16 + (l >> 4) * 4;
  const int j0 = jt * 64 + (l & 15);
#pragma unroll
  for (int n = 0; n < 4; ++n)
#pragma unroll
    for (int q = 0; q < 4; ++q)
      S[((size_t)b * T_ + i0 + q) * T_ + j0 + n * 16] = smax[n][q];
}

// ---------------------------------------------------------------------------
// r11_PW: V -> PV-B fragments (j as K dim, h as N dim), hi/lo.  (verified)
// Runs AFTER r10_B: writes into the dead UF region.
// ---------------------------------------------------------------------------
__global__ __launch_bounds__(256) void r11_PW(const float* __restrict__ V,
                                              unsigned short* __restrict__ VPh,
                                              unsigned short* __restrict__ VPl) {
  const int tid = blockIdx.x * 256 + threadIdx.x;  // < 98304
  const int h    = tid & 127;
  const int rest = tid >> 7;
  const int jo   = rest % 96;
  const int b    = rest / 96;
  const int j0   = jo * 8;

  Pk8 hi, lo;
#pragma unroll
  for (int e = 0; e < 8; ++e) {
    const float v = V[((size_t)b * T_ + j0 + e) * H_ + h];
    const unsigned short hh = f2bf(v);
    hi.s[e] = hh;
    lo.s[e] = f2bf(v - bf2f(hh));
  }
  const size_t frag = ((size_t)b * 8 + (h >> 4)) * 24 + (j0 >> 5);
  const size_t off = frag * 512 + ((size_t)((h & 15) + 16 * ((j0 >> 3) & 3))) * 8;
  *reinterpret_cast<uint4*>(VPh + off) = hi.u4;
  *reinterpret_cast<uint4*>(VPl + off) = lo.u4;
}

// ---------------------------------------------------------------------------
// r11_C: softmax -> P bf16 in LDS -> PV via MFMA  (verified)
// ---------------------------------------------------------------------------
__global__ __launch_bounds__(256) void r11_C(const unsigned short* __restrict__ VPh,
                                             const unsigned short* __restrict__ VPl,
                                             const float* __restrict__ S,
                                             float* __restrict__ O) {
  __shared__ __align__(16) unsigned short sP[16][776];
  __shared__ float sInv[16];
  const int blk = blockIdx.x;
  const int it = blk % (T_ / 16);
  const int b  = blk / (T_ / 16);
  const int t  = threadIdx.x;
  const int r  = t >> 4;
  const int c  = t & 15;

  const float* Srow = S + (size_t)(b * T_ + it * 16) * T_;

  float4 buf[12];
  float m = -3.4e38f;
#pragma unroll
  for (int q = 0; q < 12; ++q) {
    const int j4 = c + q * 16;
    const float4 x = *reinterpret_cast<const float4*>(&Srow[r * T_ + j4 * 4]);
    buf[q] = x;
    m = fmaxf(m, fmaxf(fmaxf(x.x, x.y), fmaxf(x.z, x.w)));
  }
  m = fmaxf(m, __shfl_xor(m, 1));
  m = fmaxf(m, __shfl_xor(m, 2));
  m = fmaxf(m, __shfl_xor(m, 4));
  m = fmaxf(m, __shfl_xor(m, 8));

  float l = 0.f;
#pragma unroll
  for (int q = 0; q < 12; ++q) {
    const int j4 = c + q * 16;
    float4 e;
    e.x = expf(buf[q].x - m);
    e.y = expf(buf[q].y - m);
    e.z = expf(buf[q].z - m);
    e.w = expf(buf[q].w - m);
    l += (e.x + e.y) + (e.z + e.w);
    ushort4 pb;
    pb.x = f2bf(e.x); pb.y = f2bf(e.y); pb.z = f2bf(e.z); pb.w = f2bf(e.w);
    *reinterpret_cast<ushort4*>(&sP[r][j4 * 4]) = pb;
  }
  l += __shfl_xor(l, 1);
  l += __shfl_xor(l, 2);
  l += __shfl_xor(l, 4);
  l += __shfl_xor(l, 8);
  if (c == 0) sInv[r] = 1.0f / l;
  __syncthreads();

  const int w  = t >> 6;
  const int lv = t & 63;
  f32x4 acc0, acc1;
#pragma unroll
  for (int q = 0; q < 4; ++q) { acc0[q] = 0.f; acc1[q] = 0.f; }

  const int arow = lv & 15;
  const int koct = lv >> 4;
#pragma unroll
  for (int ks = 0; ks < 24; ++ks) {
    const short8v pa =
        *reinterpret_cast<const short8v*>(&sP[arow][ks * 32 + koct * 8]);
    const size_t f0 = (((size_t)b * 8 + (w * 2 + 0)) * 24 + ks) * 512 + (size_t)lv * 8;
    const size_t f1 = (((size_t)b * 8 + (w * 2 + 1)) * 24 + ks) * 512 + (size_t)lv * 8;
    const short8v b0h = *reinterpret_cast<const short8v*>(VPh + f0);
    const short8v b0l = *reinterpret_cast<const short8v*>(VPl + f0);
    const short8v b1h = *reinterpret_cast<const short8v*>(VPh + f1);
    const short8v b1l = *reinterpret_cast<const short8v*>(VPl + f1);
    acc0 = __builtin_amdgcn_mfma_f32_16x16x32_bf16(pa, b0h, acc0, 0, 0, 0);
    acc0 = __builtin_amdgcn_mfma_f32_16x16x32_bf16(pa, b0l, acc0, 0, 0, 0);
    acc1 = __builtin_amdgcn_mfma_f32_16x16x32_bf16(pa, b1h, acc1, 0, 0, 0);
    acc1 = __builtin_amdgcn_mfma_f32_16x16x32_bf16(pa, b1l, acc1, 0, 0, 0);
  }

  const int hcol = lv & 15;
#pragma unroll
  for (int q = 0; q < 4; ++q) {
    const int irow = (lv >> 4) * 4 + q;
    const float inv = sInv[irow];
    const size_t obase = ((size_t)(b * T_ + it * 16 + irow)) * H_;
    O[obase + (w * 2 + 0) * 16 + hcol] = acc0[q] * inv;
    O[obase + (w * 2 + 1) * 16 + hcol] = acc1[q] * inv;
  }
}

// ---------------------------------------------------------------------------
extern "C" void kernel_launch(void* const* d_in, const int* in_sizes, int n_in,
                              void* d_out, int out_size, void* d_ws, size_t ws_size,
                              hipStream_t stream) {
  const float* V = (const float*)d_in[0];  // f32 [B,T,H]
  const float* W = (const float*)d_in[1];  // f32 [F,H,H]
  if (n_in >= 2 && in_sizes[0] == F_ * H_ * H_) {
    V = (const float*)d_in[1];
    W = (const float*)d_in[0];
  }
  float* O = (float*)d_out;  // f32 [B,T,H]

  const size_t s_bytes  = (size_t)B_ * T_ * T_ * 4;       // 18,874,368
  const size_t uf_bytes = (size_t)B_ * F_ * H_ * T_ * 2;  // 15,728,640
  const size_t vf_bytes = (size_t)B_ * H_ * T_ * 2;       //  1,572,864
  const size_t wf_bytes = (size_t)F_ * H_ * H_ * 2;       //    327,680
  const size_t need = s_bytes + 2 * uf_bytes + 2 * vf_bytes;  // 53,477,376
  if (ws_size < need) return;

  char* base = (char*)d_ws;
  float* S  = (float*)base;  // [B,T,T]
  // WF overlays S: read only by r12_A, which completes before r10_B writes S.
  unsigned short* WFh = (unsigned short*)base;
  unsigned short* WFl = (unsigned short*)(base + wf_bytes);
  unsigned short* UFh = (unsigned short*)(base + s_bytes);
  unsigned short* UFl = (unsigned short*)(base + s_bytes + uf_bytes);
  unsigned short* VFh = (unsigned short*)(base + s_bytes + 2 * uf_bytes);
  unsigned short* VFl = (unsigned short*)(base + s_bytes + 2 * uf_bytes + vf_bytes);
  // VP overlays UF: written by r11_PW only after r10_B (UF's last reader).
  unsigned short* VPh = UFh;
  unsigned short* VPl = UFh + vf_bytes / 2;

  r10_PV<<<B_ * T_ * 16 / 256, 256, 0, stream>>>(V, VFh, VFl);
  r12_PW2<<<F_ * 8 * 4 * 64 / 256, 256, 0, stream>>>(W, WFh, WFl);
  r12_A<<<B_ * F_ * (T_ / 64), 256, 0, stream>>>(VFh, VFl, WFh, WFl, UFh, UFl);
  r10_B<<<B_ * (T_ / 64) * (T_ / 64), 256, 0, stream>>>(UFh, UFl, VFh, VFl, S);
  r11_PW<<<B_ * 96 * 128 / 256, 256, 0, stream>>>(V, VPh, VPl);
  r11_C<<<B_ * (T_ / 16), 256, 0, stream>>>(VPh, VPl, S, O);
}

// Round 13
// 83.039 us; speedup vs baseline: 4.1819x; 1.0977x over previous
//
#include <hip/hip_runtime.h>
#include <hip/hip_bf16.h>

#define B_ 8
#define T_ 768
#define H_ 128
#define F_ 10

using short8v = __attribute__((ext_vector_type(8))) short;
using f32x4   = __attribute__((ext_vector_type(4))) float;

__device__ __forceinline__ float bf2f(unsigned short s) {
  union { unsigned int u; float f; } w;
  w.u = ((unsigned int)s) << 16;
  return w.f;
}
__device__ __forceinline__ unsigned short f2bf(float x) {
  __hip_bfloat16 h = __float2bfloat16(x);  // RN
  return *reinterpret_cast<unsigned short*>(&h);
}
union Pk8 { uint4 u4; unsigned short s[8]; };

// ---------------------------------------------------------------------------
// r10_PV: V -> row-major fragments (rows = T index, K = H dim), hi/lo. (verified)
// ---------------------------------------------------------------------------
__global__ __launch_bounds__(256) void r10_PV(const float* __restrict__ V,
                                              unsigned short* __restrict__ VFh,
                                              unsigned short* __restrict__ VFl) {
  const int task = blockIdx.x * 256 + threadIdx.x;
  const int b  = task / (T_ * 16);
  const int r  = task % (T_ * 16);
  const int j  = r >> 4;
  const int ko = r & 15;
  const float* src = V + ((size_t)b * T_ + j) * H_ + ko * 8;
  const float4 v0 = *reinterpret_cast<const float4*>(src);
  const float4 v1 = *reinterpret_cast<const float4*>(src + 4);
  const float vv[8] = {v0.x, v0.y, v0.z, v0.w, v1.x, v1.y, v1.z, v1.w};
  Pk8 hi, lo;
#pragma unroll
  for (int e = 0; e < 8; ++e) {
    const unsigned short h = f2bf(vv[e]);
    hi.s[e] = h;
    lo.s[e] = f2bf(vv[e] - bf2f(h));
  }
  const size_t frag = ((size_t)b * 48 + (j >> 4)) * 4 + (ko >> 2);
  const size_t off = frag * 512 + ((size_t)((j & 15) + 16 * (ko & 3))) * 8;
  *reinterpret_cast<uint4*>(VFh + off) = hi.u4;
  *reinterpret_cast<uint4*>(VFl + off) = lo.u4;
}

// ---------------------------------------------------------------------------
// r12_PW2: W -> B-operand fragments (K = h, N = k), hi/lo.  (verified)
// ---------------------------------------------------------------------------
__global__ __launch_bounds__(256) void r12_PW2(const float* __restrict__ W,
                                               unsigned short* __restrict__ WFh,
                                               unsigned short* __restrict__ WFl) {
  const int tid = blockIdx.x * 256 + threadIdx.x;  // < 320*64
  const int frag = tid >> 6;
  const int l    = tid & 63;
  const int f    = frag >> 5;
  const int rest = frag & 31;
  const int n    = rest >> 2;
  const int ks   = rest & 3;
  const int k  = n * 16 + (l & 15);
  const int h0 = ks * 32 + ((l >> 4) * 8);
  Pk8 hi, lo;
#pragma unroll
  for (int e = 0; e < 8; ++e) {
    const float v = W[((size_t)f * H_ + h0 + e) * H_ + k];
    const unsigned short hh = f2bf(v);
    hi.s[e] = hh;
    lo.s[e] = f2bf(v - bf2f(hh));
  }
  const size_t off = (size_t)frag * 512 + (size_t)l * 8;
  *reinterpret_cast<uint4*>(WFh + off) = hi.u4;
  *reinterpret_cast<uint4*>(WFl + off) = lo.u4;
}

// ---------------------------------------------------------------------------
// r12_A: U = V @ W via split-bf16 MFMA -> UF fragments.  (verified compute)
// XCD swizzle: panel (b,it) -> XCD panel/12, matching r10_B, so the UF bytes
// this block writes are read by r10_B blocks on the SAME XCD's L2.
// grid = 960 (= 8 xcd * 12 panels * 10 f).
// ---------------------------------------------------------------------------
__global__ __launch_bounds__(256) void r12_A(const unsigned short* __restrict__ VFh,
                                             const unsigned short* __restrict__ VFl,
                                             const unsigned short* __restrict__ WFh,
                                             const unsigned short* __restrict__ WFl,
                                             unsigned short* __restrict__ UFh,
                                             unsigned short* __restrict__ UFl) {
  __shared__ __align__(16) float fl[8192];
  const int blk = blockIdx.x;
  const int x     = blk & 7;        // XCD under round-robin dispatch
  const int local = blk >> 3;       // 0..119
  const int panel = x * 12 + local / 10;  // 0..95 (b,it)-panel
  const int f     = local % 10;
  const int b  = panel / 12;
  const int it = panel % 12;
  const int t  = threadIdx.x;
  const int w  = t >> 6;
  const int l  = t & 63;

  short8v Ah[4], Al[4];
#pragma unroll
  for (int ks = 0; ks < 4; ++ks) {
    const size_t off = (((size_t)b * 48 + it * 4 + w) * 4 + ks) * 512 + (size_t)l * 8;
    Ah[ks] = *reinterpret_cast<const short8v*>(VFh + off);
    Al[ks] = *reinterpret_cast<const short8v*>(VFl + off);
  }

  f32x4 acc[8];
#pragma unroll
  for (int n = 0; n < 8; ++n)
#pragma unroll
    for (int q = 0; q < 4; ++q) acc[n][q] = 0.f;

#pragma unroll
  for (int n = 0; n < 8; ++n)
#pragma unroll
    for (int ks = 0; ks < 4; ++ks) {
      const size_t off = ((size_t)(f * 8 + n) * 4 + ks) * 512 + (size_t)l * 8;
      const short8v bh = *reinterpret_cast<const short8v*>(WFh + off);
      const short8v bl = *reinterpret_cast<const short8v*>(WFl + off);
      acc[n] = __builtin_amdgcn_mfma_f32_16x16x32_bf16(Ah[ks], bh, acc[n], 0, 0, 0);
      acc[n] = __builtin_amdgcn_mfma_f32_16x16x32_bf16(Al[ks], bh, acc[n], 0, 0, 0);
      acc[n] = __builtin_amdgcn_mfma_f32_16x16x32_bf16(Ah[ks], bl, acc[n], 0, 0, 0);
    }

#pragma unroll
  for (int n = 0; n < 8; ++n)
#pragma unroll
    for (int q = 0; q < 4; ++q) {
      const int i_loc = w * 16 + (l >> 4) * 4 + q;
      const int k = n * 16 + (l & 15);
      const int ll = (i_loc & 15) + 16 * ((k >> 3) & 3);
      fl[((w * 4 + (k >> 5)) << 9) + ll * 8 + (k & 7)] = acc[n][q];
    }
  __syncthreads();
  const size_t ufbase = ((size_t)(b * F_ + f) * 192 + it * 16) * 512;
#pragma unroll
  for (int rr = 0; rr < 4; ++rr) {
    const int idx = rr * 2048 + t * 8;
    const float4 v0 = *reinterpret_cast<const float4*>(&fl[idx]);
    const float4 v1 = *reinterpret_cast<const float4*>(&fl[idx + 4]);
    const float vv[8] = {v0.x, v0.y, v0.z, v0.w, v1.x, v1.y, v1.z, v1.w};
    Pk8 hi, lo;
#pragma unroll
    for (int e = 0; e < 8; ++e) {
      const unsigned short h = f2bf(vv[e]);
      hi.s[e] = h;
      lo.s[e] = f2bf(vv[e] - bf2f(h));
    }
    *reinterpret_cast<uint4*>(UFh + ufbase + idx) = hi.u4;
    *reinterpret_cast<uint4*>(UFl + ufbase + idx) = lo.u4;
  }
}

// ---------------------------------------------------------------------------
// r10_B: S = max_f U_f V^T via split-bf16 MFMA.  (verified compute)
// XCD swizzle: the 12 jt-blocks sharing one (b,it) U-panel land on ONE XCD,
// consecutively -> U-panel fetched into exactly one L2, 12x reuse.
// grid = 1152 (= 8 xcd * 12 panels * 12 jt).
// ---------------------------------------------------------------------------
__global__ __launch_bounds__(256) void r10_B(const unsigned short* __restrict__ UFh,
                                             const unsigned short* __restrict__ UFl,
                                             const unsigned short* __restrict__ VFh,
                                             const unsigned short* __restrict__ VFl,
                                             float* __restrict__ S) {
  const int blk = blockIdx.x;
  const int x     = blk & 7;
  const int local = blk >> 3;             // 0..143
  const int panel = x * 12 + local / 12;  // 0..95
  const int jt    = local % 12;
  const int b  = panel / 12;
  const int it = panel % 12;
  const int w  = threadIdx.x >> 6;
  const int l  = threadIdx.x & 63;

  short8v Bh[4][4], Bl[4][4];
#pragma unroll
  for (int n = 0; n < 4; ++n)
#pragma unroll
    for (int ks = 0; ks < 4; ++ks) {
      const size_t off =
          (((size_t)b * 48 + jt * 4 + n) * 4 + ks) * 512 + (size_t)l * 8;
      Bh[n][ks] = *reinterpret_cast<const short8v*>(VFh + off);
      Bl[n][ks] = *reinterpret_cast<const short8v*>(VFl + off);
    }

  f32x4 smax[4];
#pragma unroll
  for (int n = 0; n < 4; ++n)
#pragma unroll
    for (int q = 0; q < 4; ++q) smax[n][q] = -3.4e38f;

  for (int f = 0; f < F_; ++f) {
    const size_t abase = ((size_t)(b * F_ + f) * 48 + it * 4 + w) * 4;
    short8v Ah[4], Al[4];
#pragma unroll
    for (int ks = 0; ks < 4; ++ks) {
      const size_t off = (abase + ks) * 512 + (size_t)l * 8;
      Ah[ks] = *reinterpret_cast<const short8v*>(UFh + off);
      Al[ks] = *reinterpret_cast<const short8v*>(UFl + off);
    }
    f32x4 acc[4];
#pragma unroll
    for (int n = 0; n < 4; ++n)
#pragma unroll
      for (int q = 0; q < 4; ++q) acc[n][q] = 0.f;
#pragma unroll
    for (int ks = 0; ks < 4; ++ks)
#pragma unroll
      for (int n = 0; n < 4; ++n) {
        acc[n] = __builtin_amdgcn_mfma_f32_16x16x32_bf16(Ah[ks], Bh[n][ks], acc[n], 0, 0, 0);
        acc[n] = __builtin_amdgcn_mfma_f32_16x16x32_bf16(Al[ks], Bh[n][ks], acc[n], 0, 0, 0);
        acc[n] = __builtin_amdgcn_mfma_f32_16x16x32_bf16(Ah[ks], Bl[n][ks], acc[n], 0, 0, 0);
      }
#pragma unroll
    for (int n = 0; n < 4; ++n)
#pragma unroll
      for (int q = 0; q < 4; ++q) smax[n][q] = fmaxf(smax[n][q], acc[n][q]);
  }

  const int i0 = it * 64 + w * 16 + (l >> 4) * 4;
  const int j0 = jt * 64 + (l & 15);
#pragma unroll
  for (int n = 0; n < 4; ++n)
#pragma unroll
    for (int q = 0; q < 4; ++q)
      S[((size_t)b * T_ + i0 + q) * T_ + j0 + n * 16] = smax[n][q];
}

// ---------------------------------------------------------------------------
// r11_PW: V -> PV-B fragments (j as K dim, h as N dim), hi/lo.  (verified)
// ---------------------------------------------------------------------------
__global__ __launch_bounds__(256) void r11_PW(const float* __restrict__ V,
                                              unsigned short* __restrict__ VPh,
                                              unsigned short* __restrict__ VPl) {
  const int tid = blockIdx.x * 256 + threadIdx.x;  // < 98304
  const int h    = tid & 127;
  const int rest = tid >> 7;
  const int jo   = rest % 96;
  const int b    = rest / 96;
  const int j0   = jo * 8;

  Pk8 hi, lo;
#pragma unroll
  for (int e = 0; e < 8; ++e) {
    const float v = V[((size_t)b * T_ + j0 + e) * H_ + h];
    const unsigned short hh = f2bf(v);
    hi.s[e] = hh;
    lo.s[e] = f2bf(v - bf2f(hh));
  }
  const size_t frag = ((size_t)b * 8 + (h >> 4)) * 24 + (j0 >> 5);
  const size_t off = frag * 512 + ((size_t)((h & 15) + 16 * ((j0 >> 3) & 3))) * 8;
  *reinterpret_cast<uint4*>(VPh + off) = hi.u4;
  *reinterpret_cast<uint4*>(VPl + off) = lo.u4;
}

// ---------------------------------------------------------------------------
// r11_C: softmax -> P bf16 in LDS -> PV via MFMA  (verified)
// ---------------------------------------------------------------------------
__global__ __launch_bounds__(256) void r11_C(const unsigned short* __restrict__ VPh,
                                             const unsigned short* __restrict__ VPl,
                                             const float* __restrict__ S,
                                             float* __restrict__ O) {
  __shared__ __align__(16) unsigned short sP[16][776];
  __shared__ float sInv[16];
  const int blk = blockIdx.x;
  const int it = blk % (T_ / 16);
  const int b  = blk / (T_ / 16);
  const int t  = threadIdx.x;
  const int r  = t >> 4;
  const int c  = t & 15;

  const float* Srow = S + (size_t)(b * T_ + it * 16) * T_;

  float4 buf[12];
  float m = -3.4e38f;
#pragma unroll
  for (int q = 0; q < 12; ++q) {
    const int j4 = c + q * 16;
    const float4 x = *reinterpret_cast<const float4*>(&Srow[r * T_ + j4 * 4]);
    buf[q] = x;
    m = fmaxf(m, fmaxf(fmaxf(x.x, x.y), fmaxf(x.z, x.w)));
  }
  m = fmaxf(m, __shfl_xor(m, 1));
  m = fmaxf(m, __shfl_xor(m, 2));
  m = fmaxf(m, __shfl_xor(m, 4));
  m = fmaxf(m, __shfl_xor(m, 8));

  float l = 0.f;
#pragma unroll
  for (int q = 0; q < 12; ++q) {
    const int j4 = c + q * 16;
    float4 e;
    e.x = expf(buf[q].x - m);
    e.y = expf(buf[q].y - m);
    e.z = expf(buf[q].z - m);
    e.w = expf(buf[q].w - m);
    l += (e.x + e.y) + (e.z + e.w);
    ushort4 pb;
    pb.x = f2bf(e.x); pb.y = f2bf(e.y); pb.z = f2bf(e.z); pb.w = f2bf(e.w);
    *reinterpret_cast<ushort4*>(&sP[r][j4 * 4]) = pb;
  }
  l += __shfl_xor(l, 1);
  l += __shfl_xor(l, 2);
  l += __shfl_xor(l, 4);
  l += __shfl_xor(l, 8);
  if (c == 0) sInv[r] = 1.0f / l;
  __syncthreads();

  const int w  = t >> 6;
  const int lv = t & 63;
  f32x4 acc0, acc1;
#pragma unroll
  for (int q = 0; q < 4; ++q) { acc0[q] = 0.f; acc1[q] = 0.f; }

  const int arow = lv & 15;
  const int koct = lv >> 4;
#pragma unroll
  for (int ks = 0; ks < 24; ++ks) {
    const short8v pa =
        *reinterpret_cast<const short8v*>(&sP[arow][ks * 32 + koct * 8]);
    const size_t f0 = (((size_t)b * 8 + (w * 2 + 0)) * 24 + ks) * 512 + (size_t)lv * 8;
    const size_t f1 = (((size_t)b * 8 + (w * 2 + 1)) * 24 + ks) * 512 + (size_t)lv * 8;
    const short8v b0h = *reinterpret_cast<const short8v*>(VPh + f0);
    const short8v b0l = *reinterpret_cast<const short8v*>(VPl + f0);
    const short8v b1h = *reinterpret_cast<const short8v*>(VPh + f1);
    const short8v b1l = *reinterpret_cast<const short8v*>(VPl + f1);
    acc0 = __builtin_amdgcn_mfma_f32_16x16x32_bf16(pa, b0h, acc0, 0, 0, 0);
    acc0 = __builtin_amdgcn_mfma_f32_16x16x32_bf16(pa, b0l, acc0, 0, 0, 0);
    acc1 = __builtin_amdgcn_mfma_f32_16x16x32_bf16(pa, b1h, acc1, 0, 0, 0);
    acc1 = __builtin_amdgcn_mfma_f32_16x16x32_bf16(pa, b1l, acc1, 0, 0, 0);
  }

  const int hcol = lv & 15;
#pragma unroll
  for (int q = 0; q < 4; ++q) {
    const int irow = (lv >> 4) * 4 + q;
    const float inv = sInv[irow];
    const size_t obase = ((size_t)(b * T_ + it * 16 + irow)) * H_;
    O[obase + (w * 2 + 0) * 16 + hcol] = acc0[q] * inv;
    O[obase + (w * 2 + 1) * 16 + hcol] = acc1[q] * inv;
  }
}

// ---------------------------------------------------------------------------
extern "C" void kernel_launch(void* const* d_in, const int* in_sizes, int n_in,
                              void* d_out, int out_size, void* d_ws, size_t ws_size,
                              hipStream_t stream) {
  const float* V = (const float*)d_in[0];  // f32 [B,T,H]
  const float* W = (const float*)d_in[1];  // f32 [F,H,H]
  if (n_in >= 2 && in_sizes[0] == F_ * H_ * H_) {
    V = (const float*)d_in[1];
    W = (const float*)d_in[0];
  }
  float* O = (float*)d_out;  // f32 [B,T,H]

  const size_t s_bytes  = (size_t)B_ * T_ * T_ * 4;       // 18,874,368
  const size_t uf_bytes = (size_t)B_ * F_ * H_ * T_ * 2;  // 15,728,640
  const size_t vf_bytes = (size_t)B_ * H_ * T_ * 2;       //  1,572,864
  const size_t wf_bytes = (size_t)F_ * H_ * H_ * 2;       //    327,680
  const size_t need = s_bytes + 2 * uf_bytes + 2 * vf_bytes;  // 53,477,376
  if (ws_size < need) return;

  char* base = (char*)d_ws;
  float* S  = (float*)base;  // [B,T,T]
  // WF overlays S: read only by r12_A, which completes before r10_B writes S.
  unsigned short* WFh = (unsigned short*)base;
  unsigned short* WFl = (unsigned short*)(base + wf_bytes);
  unsigned short* UFh = (unsigned short*)(base + s_bytes);
  unsigned short* UFl = (unsigned short*)(base + s_bytes + uf_bytes);
  unsigned short* VFh = (unsigned short*)(base + s_bytes + 2 * uf_bytes);
  unsigned short* VFl = (unsigned short*)(base + s_bytes + 2 * uf_bytes + vf_bytes);
  // VP overlays UF: written by r11_PW only after r10_B (UF's last reader).
  unsigned short* VPh = UFh;
  unsigned short* VPl = UFh + vf_bytes / 2;

  r10_PV<<<B_ * T_ * 16 / 256, 256, 0, stream>>>(V, VFh, VFl);
  r12_PW2<<<F_ * 8 * 4 * 64 / 256, 256, 0, stream>>>(W, WFh, WFl);
  r12_A<<<B_ * F_ * (T_ / 64), 256, 0, stream>>>(VFh, VFl, WFh, WFl, UFh, UFl);
  r10_B<<<B_ * (T_ / 64) * (T_ / 64), 256, 0, stream>>>(UFh, UFl, VFh, VFl, S);
  r11_PW<<<B_ * 96 * 128 / 256, 256, 0, stream>>>(V, VPh, VPl);
  r11_C<<<B_ * (T_ / 16), 256, 0, stream>>>(VPh, VPl, S, O);
}